// Round 5
// baseline (11144.088 us; speedup 1.0000x reference)
//
#include <hip/hip_runtime.h>
#include <math.h>

#define B 32
#define T 128
#define H 512
#define E 512
#define ODIM 256
#define STEPS 16
#define G3 1536  // 3*H
#define BH (B * H)

typedef float4 f4;

__device__ __forceinline__ float sigmoidf_(float x) { return 1.0f / (1.0f + __expf(-x)); }
__device__ __forceinline__ float tanh_fast(float x) {
    float t = __expf(-2.0f * fabsf(x));
    float r = (1.0f - t) / (1.0f + t);
    return __builtin_copysignf(r, x);
}
__device__ __forceinline__ void fma4(f4& a, float s, const f4 w) {
    a.x = fmaf(s, w.x, a.x); a.y = fmaf(s, w.y, a.y);
    a.z = fmaf(s, w.z, a.z); a.w = fmaf(s, w.w, a.w);
}
__device__ __forceinline__ void add4(f4& a, const f4 b) {
    a.x += b.x; a.y += b.y; a.z += b.z; a.w += b.w;
}
__device__ __forceinline__ float dot4(const f4 a, const f4 b) {
    return fmaf(a.x, b.x, fmaf(a.y, b.y, fmaf(a.z, b.z, a.w * b.w)));
}

// ---- staged activation layout: f4 slot [kq][b] with XOR swizzle (conflict-free both ways) ----
// stage32: src [32][512] -> st;  read ld32(st, kq, b) = h[4kq..4kq+3][b]
__device__ __forceinline__ void stage32(const float* __restrict__ src, float* __restrict__ st,
                                        int tid, int nthr) {
    f4* d = (f4*)st;
    const f4* s = (const f4*)src;
    for (int idx = tid; idx < 4096; idx += nthr) {
        int bb = idx >> 7, kq = idx & 127;
        d[kq * 32 + (bb ^ (kq & 31))] = s[idx];
    }
}
__device__ __forceinline__ f4 ld32(const float* __restrict__ st, int kq, int b) {
    return ((const f4*)st)[kq * 32 + (b ^ (kq & 31))];
}
// stage16: src [16][512]
__device__ __forceinline__ void stage16(const float* __restrict__ src, float* __restrict__ st,
                                        int tid, int nthr) {
    f4* d = (f4*)st;
    const f4* s = (const f4*)src;
    for (int idx = tid; idx < 2048; idx += nthr) {
        int bb = idx >> 7, kq = idx & 127;
        d[kq * 16 + (bb ^ (kq & 15))] = s[idx];
    }
}
__device__ __forceinline__ f4 ld16(const float* __restrict__ st, int kq, int b) {
    return ((const f4*)st)[kq * 16 + (b ^ (kq & 15))];
}
// stageF: src [32][256]
__device__ __forceinline__ void stageF(const float* __restrict__ src, float* __restrict__ st,
                                       int tid, int nthr) {
    f4* d = (f4*)st;
    const f4* s = (const f4*)src;
    for (int idx = tid; idx < 2048; idx += nthr) {
        int bb = idx >> 6, oq = idx & 63;
        d[oq * 32 + (bb ^ (oq & 31))] = s[idx];
    }
}

// ---------------- 32x32 tiled transpose (only used for Wk) ----------------
__global__ void transpose_kernel(const float* __restrict__ in, float* __restrict__ out,
                                 int R, int C, int ldin) {
    __shared__ float tile[32][33];
    int r0 = blockIdx.x * 32, c0 = blockIdx.y * 32;
    int tx = threadIdx.x & 31, ty = threadIdx.x >> 5;  // 32x8
#pragma unroll
    for (int k = 0; k < 4; ++k) {
        int r = r0 + ty + k * 8;
        tile[ty + k * 8][tx] = in[(size_t)r * ldin + c0 + tx];
    }
    __syncthreads();
#pragma unroll
    for (int k = 0; k < 4; ++k) {
        int c = c0 + ty + k * 8;
        out[(size_t)c * R + r0 + tx] = tile[tx][ty + k * 8];
    }
}

// ---------------- kpT[b][c][t] = sum_k enc[b*T+t][k] * WkT[k][c] ----------------
__global__ void __launch_bounds__(256) kproj_gemm_kernel(const float* __restrict__ A,
                                                         const float* __restrict__ Bt,
                                                         float* __restrict__ kpT) {
    __shared__ float As[64][68];
    __shared__ float Bs[64][64];
    int r0 = blockIdx.x * 64, c0 = blockIdx.y * 64;
    int tid = threadIdx.x;
    int tx = tid & 15, ty = tid >> 4;  // 16x16, 4x4 micro-tile
    float acc[4][4] = {};
    for (int k0 = 0; k0 < 512; k0 += 64) {
#pragma unroll
        for (int i = 0; i < 4; ++i) {
            int row = i * 16 + ty, col = tx * 4;
            f4 av = *(const f4*)(A + (size_t)(r0 + row) * 512 + k0 + col);
            As[row][col] = av.x; As[row][col + 1] = av.y; As[row][col + 2] = av.z; As[row][col + 3] = av.w;
            f4 bv = *(const f4*)(Bt + (size_t)(k0 + row) * 512 + c0 + col);
            *(f4*)&Bs[row][col] = bv;
        }
        __syncthreads();
#pragma unroll 8
        for (int kk = 0; kk < 64; ++kk) {
            float a[4];
#pragma unroll
            for (int i = 0; i < 4; ++i) a[i] = As[ty * 4 + i][kk];
            f4 bv = *(const f4*)&Bs[kk][tx * 4];
#pragma unroll
            for (int i = 0; i < 4; ++i) {
                acc[i][0] += a[i] * bv.x; acc[i][1] += a[i] * bv.y;
                acc[i][2] += a[i] * bv.z; acc[i][3] += a[i] * bv.w;
            }
        }
        __syncthreads();
    }
#pragma unroll
    for (int i = 0; i < 4; ++i) {
        int r = r0 + ty * 4 + i;
        int b = r >> 7, t = r & 127;
#pragma unroll
        for (int j = 0; j < 4; ++j) {
            int c = c0 + tx * 4 + j;
            kpT[((size_t)b * H + c) * T + t] = acc[i][j];
        }
    }
}

// ---------------- init: copy hidden; block 0 computes inp0 = emb(ones) for all b ----------------
__global__ void __launch_bounds__(512) init_kernel(const float* __restrict__ hidden,
                                                   const float* __restrict__ emb_W,
                                                   const float* __restrict__ emb_b,
                                                   float* __restrict__ h0, float* __restrict__ h1,
                                                   float* __restrict__ inp) {
    int b = blockIdx.x, tid = threadIdx.x;
    h0[b * H + tid] = hidden[b * H + tid];
    h1[b * H + tid] = hidden[BH + b * H + tid];
    if (b == 0) {
        const f4* row = (const f4*)(emb_W + (size_t)tid * ODIM);
        float acc = emb_b[tid];
#pragma unroll 8
        for (int o = 0; o < ODIM / 4; ++o) { f4 v = row[o]; acc += v.x + v.y + v.z + v.w; }
        for (int bb = 0; bb < B; ++bb) inp[bb * E + tid] = acc;
    }
}

// ---------------- attn1: qproj (blocks<nb_q: 64 x {8j, all b}) + lin(prev) (8 x {32o, all b}) ----------------
__global__ void __launch_bounds__(256) attn1_kernel(
    int nb_q, const float* __restrict__ h1cur, const float* __restrict__ Wq,
    float* __restrict__ q, const float* __restrict__ last_W,
    const float* __restrict__ last_b, const float* __restrict__ target_step,
    const int* __restrict__ mask_step, float* __restrict__ f,
    float* __restrict__ out_step) {
    __shared__ __align__(16) float sh[16384];  // 64 KB staged h1 [k][b]
    int tid = threadIdx.x;
    stage32(h1cur, sh, tid, 256);
    __syncthreads();
    if ((int)blockIdx.x < nb_q) {
        int j0 = blockIdx.x * 8;
        int b = tid >> 3, j = tid & 7, jg = j0 + j;
        const f4* w = (const f4*)(Wq + (size_t)jg * H);
        float acc = 0.f;
#pragma unroll 8
        for (int kq = 0; kq < 128; ++kq) acc += dot4(w[kq], ld32(sh, kq, b));
        q[b * H + jg] = acc;
    } else {
        int o0 = (blockIdx.x - nb_q) * 32;
        int o = tid & 31, bq = tid >> 5, og = o0 + o;
        const f4* w = (const f4*)(last_W + (size_t)og * H);
        f4 acc = {0, 0, 0, 0};
#pragma unroll 4
        for (int kq = 0; kq < 128; ++kq) {
            f4 wv_ = w[kq];
            acc.x += dot4(wv_, ld32(sh, kq, bq * 4 + 0));
            acc.y += dot4(wv_, ld32(sh, kq, bq * 4 + 1));
            acc.z += dot4(wv_, ld32(sh, kq, bq * 4 + 2));
            acc.w += dot4(wv_, ld32(sh, kq, bq * 4 + 3));
        }
        float lb = last_b[og];
        float av[4] = {acc.x, acc.y, acc.z, acc.w};
#pragma unroll
        for (int i = 0; i < 4; ++i) {
            int b = bq * 4 + i;
            float lin = av[i] + lb;
            float ff = mask_step[b] ? target_step[b * ODIM + og] : lin;
            f[b * ODIM + og] = ff;
            out_step[b * ODIM + og] = ff;
        }
    }
}

// ---------------- attn2 (1024 thr): scores+softmax+ctx (32 blk) + emb(prev) (16 blk) ----------------
__global__ void __launch_bounds__(1024) attn2_kernel(
    int nb_a, const float* __restrict__ q, const float* __restrict__ kpT,
    const float* __restrict__ wv, const float* __restrict__ enc,
    float* __restrict__ ctx, float* __restrict__ attn_out,
    const float* __restrict__ f, const float* __restrict__ emb_W,
    const float* __restrict__ emb_b, float* __restrict__ inp) {
    __shared__ __align__(16) float shq[H];
    __shared__ __align__(16) float shwv[H];
    __shared__ __align__(16) float part[1024];
    __shared__ __align__(16) f4 part4[1024];
    __shared__ float sw[T];
    __shared__ float red[4];
    __shared__ __align__(16) float stF[8192];  // 32 KB (emb path)
    int tid = threadIdx.x;
    if ((int)blockIdx.x < nb_a) {
        int b = blockIdx.x;
        if (tid < 128) ((f4*)shq)[tid] = ((const f4*)(q + (size_t)b * H))[tid];
        else if (tid < 256) ((f4*)shwv)[tid - 128] = ((const f4*)wv)[tid - 128];
        __syncthreads();
        {   // scores: 128 t x 8 j-slices
            int t = tid & 127, js = tid >> 7;
            const float* kp = kpT + (size_t)b * H * T + (size_t)js * 64 * T + t;
            float sa = 0.f;
#pragma unroll 4
            for (int jj = 0; jj < 64; ++jj) {
                int j = js * 64 + jj;
                sa += tanh_fast(shq[j] + kp[(size_t)jj * T]) * shwv[j];
            }
            part[tid] = sa;
        }
        __syncthreads();
        if (tid < 128) {
            float sc = part[tid];
#pragma unroll
            for (int r = 1; r < 8; ++r) sc += part[r * 128 + tid];
            part[tid] = sc;
            float m = sc;
            for (int off = 32; off; off >>= 1) m = fmaxf(m, __shfl_xor(m, off));
            if ((tid & 63) == 0) red[tid >> 6] = m;
        }
        __syncthreads();
        if (tid < 128) {
            float M = fmaxf(red[0], red[1]);
            float e = __expf(part[tid] - M);
            sw[tid] = e;
            float s = e;
            for (int off = 32; off; off >>= 1) s += __shfl_xor(s, off);
            if ((tid & 63) == 0) red[2 + (tid >> 6)] = s;
        }
        __syncthreads();
        if (tid < 128) {
            float w_ = sw[tid] / (red[2] + red[3]);
            sw[tid] = w_;
            attn_out[(size_t)b * T + tid] = w_;
        }
        __syncthreads();
        {   // ctx: 128 c-quads x 8 t-slices
            int cq = tid & 127, th = tid >> 7;
            const f4* e4 = (const f4*)enc;
            f4 acc = {0, 0, 0, 0};
            int t0 = th * 16;
#pragma unroll 8
            for (int t2 = t0; t2 < t0 + 16; ++t2)
                fma4(acc, sw[t2], e4[((size_t)b * T + t2) * 128 + cq]);
            part4[tid] = acc;
        }
        __syncthreads();
        if (tid < 128) {
            f4 s = part4[tid];
#pragma unroll
            for (int r = 1; r < 8; ++r) add4(s, part4[r * 128 + tid]);
            ((f4*)(ctx + (size_t)b * H))[tid] = s;
        }
    } else {
        int e0 = (blockIdx.x - nb_a) * 32;
        stageF(f, stF, tid, 1024);
        __syncthreads();
        int b = tid >> 5, e = tid & 31, eg = e0 + e;
        const f4* w = (const f4*)(emb_W + (size_t)eg * ODIM);
        float acc = 0.f;
#pragma unroll 8
        for (int oq = 0; oq < 64; ++oq) {
            f4 fv = ((const f4*)stF)[oq * 32 + (b ^ (oq & 31))];
            acc += dot4(w[oq], fv);
        }
        inp[b * E + eg] = acc + emb_b[eg];
    }
}

// ---------------- gi: 48 blk gi_ctx = bi0 + ctx@Wi0[:, :512].T ; 48 blk gi_emb = inp@Wi0[:, 512:].T ----------------
__global__ void __launch_bounds__(256) gi_kernel(
    const float* __restrict__ ctx, const float* __restrict__ inp,
    const float* __restrict__ Wi0, const float* __restrict__ bi0,
    float* __restrict__ gi_ctx, float* __restrict__ gi_emb_i) {
    __shared__ __align__(16) float sh[16384];
    int tid = threadIdx.x;
    int bid = blockIdx.x;
    bool isC = bid < 48;
    int c0 = (isC ? bid : bid - 48) * 32;
    stage32(isC ? ctx : inp, sh, tid, 256);
    __syncthreads();
    int c = tid & 31, bq = tid >> 5, cg = c0 + c;
    const f4* w = (const f4*)(Wi0 + (size_t)cg * (E + H) + (isC ? 0 : H));
    f4 acc = {0, 0, 0, 0};
#pragma unroll 4
    for (int kq = 0; kq < 128; ++kq) {
        f4 wv_ = w[kq];
        acc.x += dot4(wv_, ld32(sh, kq, bq * 4 + 0));
        acc.y += dot4(wv_, ld32(sh, kq, bq * 4 + 1));
        acc.z += dot4(wv_, ld32(sh, kq, bq * 4 + 2));
        acc.w += dot4(wv_, ld32(sh, kq, bq * 4 + 3));
    }
    float bias = isC ? bi0[cg] : 0.f;
    float* dst = isC ? gi_ctx : gi_emb_i;
    float av[4] = {acc.x, acc.y, acc.z, acc.w};
#pragma unroll
    for (int i = 0; i < 4; ++i) dst[(size_t)(bq * 4 + i) * G3 + cg] = av[i] + bias;
}

// ---------------- fused dual GRU cell, zero weight dup, row-major weights ----------------
// l0: blocks [0,nb0=64): j0 = bid*8, all 32 b. thread = b(32) x j(8)
// l1: blocks [nb0,nb0+128): lb -> b-half (16 b), j0 = (lb>>1)*8. thread = m(2) x b(16) x j(8)
__global__ void __launch_bounds__(256) cell_kernel(
    int nb0, const float* __restrict__ h0_src, float* __restrict__ h0_dst,
    const float* __restrict__ h1_src, float* __restrict__ h1_dst,
    const float* __restrict__ gi_emb_t, const float* __restrict__ gi_ctx,
    const float* __restrict__ Wh0, const float* __restrict__ bh0,
    const float* __restrict__ Wi1, const float* __restrict__ bi1,
    const float* __restrict__ Wh1, const float* __restrict__ bh1) {
    __shared__ __align__(16) float sh[16384];  // 64 KB
    int tid = threadIdx.x;
    if ((int)blockIdx.x < nb0) {
        stage32(h0_src, sh, tid, 256);
        __syncthreads();
        int j0 = blockIdx.x * 8;
        int b = tid >> 3, j = tid & 7, jg = j0 + j;
        const f4* wr = (const f4*)(Wh0 + (size_t)jg * H);
        const f4* wz = (const f4*)(Wh0 + (size_t)(H + jg) * H);
        const f4* wn = (const f4*)(Wh0 + (size_t)(2 * H + jg) * H);
        float ar = 0.f, az = 0.f, an = 0.f;
#pragma unroll 4
        for (int kq = 0; kq < 128; ++kq) {
            f4 h = ld32(sh, kq, b);
            ar += dot4(wr[kq], h);
            az += dot4(wz[kq], h);
            an += dot4(wn[kq], h);
        }
        float gir = gi_ctx[b * G3 + jg] + gi_emb_t[b * G3 + jg];
        float giz = gi_ctx[b * G3 + H + jg] + gi_emb_t[b * G3 + H + jg];
        float gin = gi_ctx[b * G3 + 2 * H + jg] + gi_emb_t[b * G3 + 2 * H + jg];
        float r = sigmoidf_(gir + ar + bh0[jg]);
        float z = sigmoidf_(giz + az + bh0[H + jg]);
        float n = tanh_fast(gin + r * (an + bh0[2 * H + jg]));
        f4 hp4 = ld32(sh, jg >> 2, b);
        float hprev = ((const float*)&hp4)[jg & 3];
        h0_dst[b * H + jg] = (1.f - z) * n + z * hprev;
    } else {
        int lb = blockIdx.x - nb0;
        int b0 = (lb & 1) * 16, j0 = (lb >> 1) * 8;
        float* stA = sh;         // x = y0(t-1), 32 KB
        float* stB = sh + 8192;  // h1, 32 KB
        stage16(h0_src + (size_t)b0 * H, stA, tid, 256);
        stage16(h1_src + (size_t)b0 * H, stB, tid, 256);
        __syncthreads();
        int m = tid >> 7, b = (tid >> 3) & 15, j = tid & 7, jg = j0 + j;
        const float* Wm = m ? Wh1 : Wi1;
        const float* stm = m ? stB : stA;
        const f4* w0 = (const f4*)(Wm + (size_t)jg * H);
        const f4* w1 = (const f4*)(Wm + (size_t)(H + jg) * H);
        const f4* w2 = (const f4*)(Wm + (size_t)(2 * H + jg) * H);
        float a0 = 0.f, a1 = 0.f, a2 = 0.f;
#pragma unroll 4
        for (int kq = 0; kq < 128; ++kq) {
            f4 v = ld16(stm, kq, b);
            a0 += dot4(w0[kq], v);
            a1 += dot4(w1[kq], v);
            a2 += dot4(w2[kq], v);
        }
        f4 hp4 = ld16(stB, jg >> 2, b);
        float hprev = ((const float*)&hp4)[jg & 3];
        __syncthreads();
        float* part = sh;  // alias stA (x fully consumed)
        if (m == 0) {
            float* p = part + (b * 8 + j) * 3;
            p[0] = a0; p[1] = a1; p[2] = a2;
        }
        __syncthreads();
        if (m == 1) {
            const float* p = part + (b * 8 + j) * 3;
            float r = sigmoidf_(p[0] + bi1[jg] + a0 + bh1[jg]);
            float z = sigmoidf_(p[1] + bi1[H + jg] + a1 + bh1[H + jg]);
            float n = tanh_fast(p[2] + bi1[2 * H + jg] + r * (a2 + bh1[2 * H + jg]));
            h1_dst[(b0 + b) * H + jg] = (1.f - z) * n + z * hprev;
        }
    }
}

__global__ void copy_hidden_kernel(const float* __restrict__ h0, const float* __restrict__ h1,
                                   float* __restrict__ dst) {
    int i = blockIdx.x * 256 + threadIdx.x;
    dst[i] = h0[i];
    dst[BH + i] = h1[i];
}

extern "C" void kernel_launch(void* const* d_in, const int* in_sizes, int n_in,
                              void* d_out_v, int out_size, void* d_ws, size_t ws_size,
                              hipStream_t stream) {
    const float* enc = (const float*)d_in[0];
    const float* hidden = (const float*)d_in[1];
    const float* target = (const float*)d_in[2];
    const float* Wq = (const float*)d_in[3];
    const float* Wk = (const float*)d_in[4];
    const float* wv = (const float*)d_in[5];
    const float* emb_W = (const float*)d_in[6];
    const float* emb_b = (const float*)d_in[7];
    const float* Wi0 = (const float*)d_in[8];
    const float* Wh0 = (const float*)d_in[9];
    const float* bi0 = (const float*)d_in[10];
    const float* bh0 = (const float*)d_in[11];
    const float* Wi1 = (const float*)d_in[12];
    const float* Wh1 = (const float*)d_in[13];
    const float* bi1 = (const float*)d_in[14];
    const float* bh1 = (const float*)d_in[15];
    const float* last_W = (const float*)d_in[16];
    const float* last_b = (const float*)d_in[17];
    const int* tmask = (const int*)d_in[18];

    float* out = (float*)d_out_v;
    float* out_hidden = out + (size_t)STEPS * B * ODIM;
    float* out_attn = out_hidden + (size_t)2 * BH;

    float* ws = (float*)d_ws;
    float* kpT = ws;                         // 2,097,152
    float* WkT = kpT + 2097152;              // 262,144
    float* gi_emb = WkT + 262144;            // 786,432 (16 steps x B x G3)
    float* gi_ctx = gi_emb + 786432;         // 49,152
    float* h0buf = gi_ctx + 49152;           // 32,768 (2x)
    float* h1buf = h0buf + 32768;            // 32,768 (2x)
    float* qbuf = h1buf + 32768;             // 16,384
    float* ctxbuf = qbuf + 16384;            // 16,384
    float* fbuf = ctxbuf + 16384;            // 8,192
    float* inpbuf = fbuf + 8192;             // 16,384

    transpose_kernel<<<dim3(16, 16), 256, 0, stream>>>(Wk, WkT, 512, 512, 512);
    kproj_gemm_kernel<<<dim3(64, 8), 256, 0, stream>>>(enc, WkT, kpT);
    init_kernel<<<B, 512, 0, stream>>>(hidden, emb_W, emb_b, h0buf, h1buf, inpbuf);

    int p0 = 0, p1 = 0;
    for (int i = 0; i < STEPS; ++i) {
        int im1 = (i > 0) ? i - 1 : 0;
        attn1_kernel<<<(i == 0) ? 64 : 72, 256, 0, stream>>>(
            64, h1buf + (size_t)p1 * BH, Wq, qbuf, last_W, last_b,
            target + (size_t)im1 * B * ODIM, tmask + im1 * B, fbuf,
            out + (size_t)im1 * B * ODIM);
        attn2_kernel<<<(i == 0) ? 32 : 48, 1024, 0, stream>>>(
            32, qbuf, kpT, wv, enc, ctxbuf, out_attn + (size_t)i * B * T, fbuf, emb_W, emb_b,
            inpbuf);
        gi_kernel<<<96, 256, 0, stream>>>(ctxbuf, inpbuf, Wi0, bi0, gi_ctx,
                                          gi_emb + (size_t)i * B * G3);
        for (int t = 0; t <= i + 1; ++t) {
            int nb0 = (t <= i) ? 64 : 0;
            int nb1 = (t >= 1) ? 128 : 0;
            int tge = (t < 15) ? t : 15;
            cell_kernel<<<nb0 + nb1, 256, 0, stream>>>(
                nb0, h0buf + (size_t)p0 * BH, h0buf + (size_t)(p0 ^ 1) * BH,
                h1buf + (size_t)p1 * BH, h1buf + (size_t)(p1 ^ 1) * BH,
                gi_emb + (size_t)tge * B * G3, gi_ctx, Wh0, bh0, Wi1, bi1, Wh1, bh1);
            if (nb0) p0 ^= 1;
            if (nb1) p1 ^= 1;
        }
    }
    // final lin (step 15)
    attn1_kernel<<<8, 256, 0, stream>>>(0, h1buf + (size_t)p1 * BH, Wq, qbuf, last_W, last_b,
                                        target + (size_t)15 * B * ODIM, tmask + 15 * B, fbuf,
                                        out + (size_t)15 * B * ODIM);
    copy_hidden_kernel<<<64, 256, 0, stream>>>(h0buf + (size_t)p0 * BH, h1buf + (size_t)p1 * BH,
                                               out_hidden);
}